// Round 1
// baseline (43.996 us; speedup 1.0000x reference)
//
#include <hip/hip_runtime.h>
#include <math.h>

// LIF neuron forward: x (B=64, T=100, F=4096) f32, log_alpha scalar.
// u = alpha*u + x_t ; s = (u >= 1) ; u -= s. Outputs spikes (B,T,F) + mean.

constexpr int T_STEPS = 100;
constexpr int F4      = 1024;                 // 4096 / 4 floats per thread-lane vec
constexpr int BATCH   = 64;
constexpr long long TOTAL = (long long)BATCH * T_STEPS * 4096;  // 26,214,400

__global__ __launch_bounds__(256)
void lif_fwd(const float4* __restrict__ x,
             const float*  __restrict__ log_alpha,
             float4*       __restrict__ out,
             unsigned int* __restrict__ cnt) {
    int idx  = blockIdx.x * 256 + threadIdx.x;   // 0 .. 65535
    int b    = idx >> 10;                        // batch
    int f4   = idx & 1023;                       // float4 index within feature dim
    size_t base = (size_t)b * T_STEPS * F4 + f4;

    // alpha = sigmoid(log_alpha), computed in double -> correctly rounded f32
    double la = (double)log_alpha[0];
    float alpha = (float)(1.0 / (1.0 + exp(-la)));

    float4 u = make_float4(0.f, 0.f, 0.f, 0.f);
    unsigned int c = 0;

    #pragma unroll 4
    for (int t = 0; t < T_STEPS; ++t) {
        float4 xt = x[base + (size_t)t * F4];
        float4 s;
        // explicit non-fused mul+add to match numpy/XLA-CPU rounding
        u.x = __fadd_rn(__fmul_rn(alpha, u.x), xt.x);
        u.y = __fadd_rn(__fmul_rn(alpha, u.y), xt.y);
        u.z = __fadd_rn(__fmul_rn(alpha, u.z), xt.z);
        u.w = __fadd_rn(__fmul_rn(alpha, u.w), xt.w);
        s.x = (u.x >= 1.0f) ? 1.0f : 0.0f;
        s.y = (u.y >= 1.0f) ? 1.0f : 0.0f;
        s.z = (u.z >= 1.0f) ? 1.0f : 0.0f;
        s.w = (u.w >= 1.0f) ? 1.0f : 0.0f;
        u.x -= s.x;  u.y -= s.y;  u.z -= s.z;  u.w -= s.w;
        out[base + (size_t)t * F4] = s;
        c += (unsigned)(s.x + s.y + s.z + s.w);
    }

    // wave (64-lane) reduction of spike count
    for (int off = 32; off > 0; off >>= 1)
        c += __shfl_down(c, off, 64);

    __shared__ unsigned int wsum[4];
    int lane = threadIdx.x & 63;
    int wid  = threadIdx.x >> 6;
    if (lane == 0) wsum[wid] = c;
    __syncthreads();
    if (threadIdx.x == 0) {
        unsigned int s = wsum[0] + wsum[1] + wsum[2] + wsum[3];
        atomicAdd(cnt, s);   // integer -> order-independent, deterministic
    }
}

__global__ void lif_rate(const unsigned int* __restrict__ cnt,
                         float* __restrict__ rate_out) {
    rate_out[0] = (float)((double)cnt[0] / (double)TOTAL);
}

extern "C" void kernel_launch(void* const* d_in, const int* in_sizes, int n_in,
                              void* d_out, int out_size, void* d_ws, size_t ws_size,
                              hipStream_t stream) {
    const float* x  = (const float*)d_in[0];
    const float* la = (const float*)d_in[1];
    float* out = (float*)d_out;
    unsigned int* cnt = (unsigned int*)d_ws;

    hipMemsetAsync(cnt, 0, sizeof(unsigned int), stream);

    int threads = BATCH * F4;              // 65536
    lif_fwd<<<threads / 256, 256, 0, stream>>>(
        (const float4*)x, la, (float4*)out, cnt);

    lif_rate<<<1, 1, 0, stream>>>(cnt, out + TOTAL);
}

// Round 3
// 43.196 us; speedup vs baseline: 1.0185x; 1.0185x over previous
//
#include <hip/hip_runtime.h>
#include <math.h>

// LIF neuron forward: x (B=64, T=100, F=4096) f32, log_alpha scalar.
// u = alpha*u + x_t ; s = (u >= 1) ; u -= s. Outputs spikes (B,T,F) + mean.
//
// R3: float2/thread -> 512 blocks = 2 blocks/CU = 8 waves/CU for latency
// hiding; unroll 10 keeps 10 loads in flight; nontemporal stores keep x
// resident in L3. (R2 fix: use clang ext_vector for the nt-store builtin.)

typedef float f32x2 __attribute__((ext_vector_type(2)));

constexpr int T_STEPS = 100;
constexpr int F2      = 2048;                 // 4096 / 2 floats per thread
constexpr int BATCH   = 64;
constexpr long long TOTAL = (long long)BATCH * T_STEPS * 4096;  // 26,214,400

__global__ __launch_bounds__(256)
void lif_fwd(const f32x2* __restrict__ x,
             const float* __restrict__ log_alpha,
             f32x2*       __restrict__ out,
             unsigned int* __restrict__ cnt) {
    int idx  = blockIdx.x * 256 + threadIdx.x;   // 0 .. 131071
    int b    = idx >> 11;                        // batch
    int f2   = idx & 2047;                       // float2 index within feature dim
    size_t base = (size_t)b * T_STEPS * F2 + f2;

    // alpha = sigmoid(log_alpha), computed in double -> correctly rounded f32
    double la = (double)log_alpha[0];
    float alpha = (float)(1.0 / (1.0 + exp(-la)));

    f32x2 u = {0.f, 0.f};
    unsigned int c = 0;

    #pragma unroll 10
    for (int t = 0; t < T_STEPS; ++t) {
        f32x2 xt = x[base + (size_t)t * F2];
        f32x2 s;
        // explicit non-fused mul+add to match numpy/XLA-CPU rounding
        float ux = __fadd_rn(__fmul_rn(alpha, u.x), xt.x);
        float uy = __fadd_rn(__fmul_rn(alpha, u.y), xt.y);
        s.x = (ux >= 1.0f) ? 1.0f : 0.0f;
        s.y = (uy >= 1.0f) ? 1.0f : 0.0f;
        u.x = ux - s.x;
        u.y = uy - s.y;
        __builtin_nontemporal_store(s, &out[base + (size_t)t * F2]);
        c += (unsigned)(s.x + s.y);
    }

    // wave (64-lane) reduction of spike count
    for (int off = 32; off > 0; off >>= 1)
        c += __shfl_down(c, off, 64);

    __shared__ unsigned int wsum[4];
    int lane = threadIdx.x & 63;
    int wid  = threadIdx.x >> 6;
    if (lane == 0) wsum[wid] = c;
    __syncthreads();
    if (threadIdx.x == 0) {
        unsigned int s = wsum[0] + wsum[1] + wsum[2] + wsum[3];
        atomicAdd(cnt, s);   // integer -> order-independent, deterministic
    }
}

__global__ void lif_rate(const unsigned int* __restrict__ cnt,
                         float* __restrict__ rate_out) {
    rate_out[0] = (float)((double)cnt[0] / (double)TOTAL);
}

extern "C" void kernel_launch(void* const* d_in, const int* in_sizes, int n_in,
                              void* d_out, int out_size, void* d_ws, size_t ws_size,
                              hipStream_t stream) {
    const float* x  = (const float*)d_in[0];
    const float* la = (const float*)d_in[1];
    float* out = (float*)d_out;
    unsigned int* cnt = (unsigned int*)d_ws;

    (void)hipMemsetAsync(cnt, 0, sizeof(unsigned int), stream);

    int threads = BATCH * F2;              // 131072
    lif_fwd<<<threads / 256, 256, 0, stream>>>(
        (const f32x2*)x, la, (f32x2*)out, cnt);

    lif_rate<<<1, 1, 0, stream>>>(cnt, out + TOTAL);
}

// Round 4
// 37.681 us; speedup vs baseline: 1.1676x; 1.1464x over previous
//
#include <hip/hip_runtime.h>
#include <math.h>

// LIF neuron forward: x (B=64, T=100, F=4096) f32, log_alpha scalar.
// u = alpha*u + x_t ; s = (u >= 1) ; u -= s. Outputs spikes (B,T,F) + mean.
//
// R4: 1 float/thread -> 1024 blocks = 4 blocks/CU = 16 waves/CU (TLP for
// mixed read+write streams). No memset dispatch: per-block counts go to
// d_ws (plain stores), lif_rate reduces them. nt stores keep x in L3.

constexpr int T_STEPS = 100;
constexpr int F       = 4096;
constexpr int BATCH   = 64;
constexpr int NBLOCKS = BATCH * F / 256;      // 1024
constexpr long long TOTAL = (long long)BATCH * T_STEPS * F;  // 26,214,400

__global__ __launch_bounds__(256)
void lif_fwd(const float* __restrict__ x,
             const float* __restrict__ log_alpha,
             float*       __restrict__ out,
             unsigned int* __restrict__ blk_cnt) {
    int idx  = blockIdx.x * 256 + threadIdx.x;   // 0 .. 262143
    int b    = idx >> 12;                        // batch
    int f    = idx & 4095;                       // feature
    size_t base = (size_t)b * T_STEPS * F + f;

    // alpha = sigmoid(log_alpha), computed in double -> correctly rounded f32
    double la = (double)log_alpha[0];
    float alpha = (float)(1.0 / (1.0 + exp(-la)));

    float u = 0.f;
    unsigned int c = 0;

    #pragma unroll 10
    for (int t = 0; t < T_STEPS; ++t) {
        float xt = x[base + (size_t)t * F];
        // explicit non-fused mul+add to match numpy/XLA-CPU rounding
        u = __fadd_rn(__fmul_rn(alpha, u), xt);
        float s = (u >= 1.0f) ? 1.0f : 0.0f;
        u -= s;
        __builtin_nontemporal_store(s, &out[base + (size_t)t * F]);
        c += (unsigned)s;
    }

    // wave (64-lane) reduction of spike count
    for (int off = 32; off > 0; off >>= 1)
        c += __shfl_down(c, off, 64);

    __shared__ unsigned int wsum[4];
    int lane = threadIdx.x & 63;
    int wid  = threadIdx.x >> 6;
    if (lane == 0) wsum[wid] = c;
    __syncthreads();
    if (threadIdx.x == 0)
        blk_cnt[blockIdx.x] = wsum[0] + wsum[1] + wsum[2] + wsum[3];
}

__global__ __launch_bounds__(256)
void lif_rate(const unsigned int* __restrict__ blk_cnt,
              float* __restrict__ rate_out) {
    // 1024 partials, 256 threads: each sums 4, then wave+LDS reduce
    unsigned int c = 0;
    #pragma unroll
    for (int i = 0; i < NBLOCKS / 256; ++i)
        c += blk_cnt[threadIdx.x + i * 256];
    for (int off = 32; off > 0; off >>= 1)
        c += __shfl_down(c, off, 64);
    __shared__ unsigned int wsum[4];
    int lane = threadIdx.x & 63;
    int wid  = threadIdx.x >> 6;
    if (lane == 0) wsum[wid] = c;
    __syncthreads();
    if (threadIdx.x == 0) {
        unsigned int s = wsum[0] + wsum[1] + wsum[2] + wsum[3];
        rate_out[0] = (float)((double)s / (double)TOTAL);
    }
}

extern "C" void kernel_launch(void* const* d_in, const int* in_sizes, int n_in,
                              void* d_out, int out_size, void* d_ws, size_t ws_size,
                              hipStream_t stream) {
    const float* x  = (const float*)d_in[0];
    const float* la = (const float*)d_in[1];
    float* out = (float*)d_out;
    unsigned int* blk_cnt = (unsigned int*)d_ws;

    lif_fwd<<<NBLOCKS, 256, 0, stream>>>(x, la, out, blk_cnt);
    lif_rate<<<1, 256, 0, stream>>>(blk_cnt, out + TOTAL);
}